// Round 2
// baseline (144.762 us; speedup 1.0000x reference)
//
#include <hip/hip_runtime.h>

#define Bv_ 8
#define LQ 128
#define LK 256
#define Dv 32
#define ET 32
#define Hh 8
#define NH 64

// ---------------------------------------------------------------------------
// Kernel 1: prep  (896 blocks x 256 threads)
//  blocks [0, 512)    : 4 value-MLP rows per block (one per wave64) -> A, Bdv, mf
//  blocks [512, 896)  : 8 time-embedding rows per block -> qe, ke
// ---------------------------------------------------------------------------
__global__ __launch_bounds__(256) void prep_kernel(
    const float* __restrict__ qtt, const float* __restrict__ ktt,
    const float* __restrict__ value, const int* __restrict__ emb_mask,
    const float* __restrict__ w_time, const float* __restrict__ b_time,
    const float* __restrict__ w_per, const float* __restrict__ b_per,
    const float* __restrict__ vt_w1, const float* __restrict__ vt_b1,
    const float* __restrict__ ln_g, const float* __restrict__ ln_b,
    const float* __restrict__ vt_w2, const float* __restrict__ vt_b2,
    const float* __restrict__ wq, const float* __restrict__ bq,
    const float* __restrict__ wk, const float* __restrict__ bk,
    float* __restrict__ A, float* __restrict__ Bdv, float* __restrict__ mf,
    float* __restrict__ qe, float* __restrict__ ke)
{
    const int t = threadIdx.x;
    const int blk = blockIdx.x;

    if (blk < 512) {
        // ---- 4 value-MLP rows, one per wave ----
        __shared__ float vrow[4][Dv];
        __shared__ float hrow[4][NH];
        const int w = t >> 6;            // wave 0..3
        const int l = t & 63;
        const int row = blk * 4 + w;     // b*LK + k, 0..2047

        if (l < Dv) vrow[w][l] = value[row * Dv + l];
        __syncthreads();

        float h = vt_b1[l];
        #pragma unroll
        for (int d = 0; d < Dv; ++d) h += vrow[w][d] * vt_w1[d * NH + l];

        // LayerNorm over NH=64 (wave-wide butterfly)
        float s = h;
        #pragma unroll
        for (int off = 32; off > 0; off >>= 1) s += __shfl_xor(s, off);
        const float mu = s * (1.0f / NH);
        const float dc = h - mu;
        float vs = dc * dc;
        #pragma unroll
        for (int off = 32; off > 0; off >>= 1) vs += __shfl_xor(vs, off);
        const float rs = rsqrtf(vs * (1.0f / NH) + 1e-5f);
        float hn = dc * rs * ln_g[l] + ln_b[l];
        hrow[w][l] = fmaxf(hn, 0.0f);
        __syncthreads();

        if (l < Dv) {
            float dval = vt_b2[l];
            #pragma unroll
            for (int j = 0; j < NH; ++j) dval += hrow[w][j] * vt_w2[j * Dv + l];
            const float mm = (emb_mask[row * Dv + l] != 0) ? 1.0f : 0.0f;
            A[row * Dv + l]   = mm * vrow[w][l];
            Bdv[row * Dv + l] = mm * dval;
            mf[row * Dv + l]  = mm;
        }
    } else {
        // ---- 8 time-embedding rows per block ----
        const int idx = blk - 512;       // 0..383
        const int sub = t >> 5;          // 0..7
        const int j = t & 31;
        const int row = idx * 8 + sub;   // 0..3071
        __shared__ float eb[8][ET];

        float tt;
        const float *W, *bias;
        float* outp;
        if (row < Bv_ * LQ) {
            tt = qtt[row];
            W = wq; bias = bq; outp = qe + row * ET;
        } else {
            const int r2 = row - Bv_ * LQ;
            tt = ktt[r2];
            W = wk; bias = bk; outp = ke + r2 * ET;
        }
        float e;
        if (j == 0) e = tt * w_time[0] + b_time[0];
        else        e = __sinf(tt * w_per[j - 1] + b_per[j - 1]);   // |arg| < 0.6
        eb[sub][j] = e;
        __syncthreads();

        float o = bias[j];
        #pragma unroll
        for (int i = 0; i < ET; ++i) o += eb[sub][i] * W[i * ET + j];
        outp[j] = o;
    }
}

// ---------------------------------------------------------------------------
// Kernel 2: attention + output projection. One block per (b,q), 256 threads.
// Phase 2 splits k 4-ways: thread = (ks, h, d4), float4 over d.
// ---------------------------------------------------------------------------
__global__ __launch_bounds__(256) void attn_kernel(
    const float* __restrict__ qtt, const float* __restrict__ ktt,
    const float* __restrict__ w_decay,
    const float* __restrict__ A, const float* __restrict__ Bdv,
    const float* __restrict__ mf,
    const float* __restrict__ qe, const float* __restrict__ ke,
    const float* __restrict__ wo, const float* __restrict__ bo,
    float* __restrict__ out)
{
    __shared__ float Eh[Hh][LK + 4];   // +4 pad: h-addresses hit distinct banks
    __shared__ float gk[LK];
    __shared__ float4 qrow4[Hh];       // q embedding row, 8 x float4
    __shared__ float4 psN[4][64];      // per-ks partial numerators
    __shared__ float4 psD[4][64];      // per-ks partial denominators
    __shared__ float4 xsh4[64];        // x row, c = h*32+d
    __shared__ float psum[4][NH];

    const int t = threadIdx.x;
    const int bq_ = blockIdx.x;        // b*LQ + q
    const int b = bq_ >> 7;

    // ---- phase 1a: q row + decay factor ----
    if (t < ET) ((float*)qrow4)[t] = qe[bq_ * ET + t];
    {
        const float dt = qtt[bq_] - ktt[b * LK + t];
        gk[t] = dt / fmaf(w_decay[0], dt, 1.0f);
    }
    __syncthreads();

    // ---- phase 1b: exp(scores) for all 8 heads (thread = k) ----
    {
        const float4* kerow = (const float4*)(ke + (b * LK + t) * ET);
        #pragma unroll
        for (int h = 0; h < Hh; ++h) {
            const float4 kk = kerow[h];
            const float4 qq = qrow4[h];
            const float sc = 0.5f * (qq.x * kk.x + qq.y * kk.y +
                                     qq.z * kk.z + qq.w * kk.w);
            Eh[h][t] = __expf(sc);     // |sc| small -> no max subtraction
        }
    }
    __syncthreads();

    // ---- phase 2: k-reduction, 4-way k-split, float4 over d ----
    {
        const int ks = t >> 6;         // 0..3
        const int h  = (t >> 3) & 7;
        const int d4 = t & 7;
        const float4* Ab = (const float4*)(A   + (size_t)b * LK * Dv) + d4;
        const float4* Bb = (const float4*)(Bdv + (size_t)b * LK * Dv) + d4;
        const float4* Mb = (const float4*)(mf  + (size_t)b * LK * Dv) + d4;
        float4 num = {0.f, 0.f, 0.f, 0.f};
        float4 den = {0.f, 0.f, 0.f, 0.f};
        const int k0 = ks * 64;
        #pragma unroll 4
        for (int kk = 0; kk < 64; ++kk) {
            const int k = k0 + kk;
            const float e  = Eh[h][k];
            const float eg = e * gk[k];
            const float4 a = Ab[k * 8];
            const float4 bb = Bb[k * 8];
            const float4 m = Mb[k * 8];
            num.x += e * a.x + eg * bb.x;
            num.y += e * a.y + eg * bb.y;
            num.z += e * a.z + eg * bb.z;
            num.w += e * a.w + eg * bb.w;
            den.x += e * m.x;
            den.y += e * m.y;
            den.z += e * m.z;
            den.w += e * m.w;
        }
        psN[ks][t & 63] = num;
        psD[ks][t & 63] = den;
    }
    __syncthreads();

    // ---- phase 2b: cross-ks reduce + divide (64 threads) ----
    if (t < 64) {
        float4 N0 = psN[0][t], N1 = psN[1][t], N2 = psN[2][t], N3 = psN[3][t];
        float4 D0 = psD[0][t], D1 = psD[1][t], D2 = psD[2][t], D3 = psD[3][t];
        float4 x;
        x.x = (N0.x + N1.x + N2.x + N3.x) / fmaxf(D0.x + D1.x + D2.x + D3.x, 1e-30f);
        x.y = (N0.y + N1.y + N2.y + N3.y) / fmaxf(D0.y + D1.y + D2.y + D3.y, 1e-30f);
        x.z = (N0.z + N1.z + N2.z + N3.z) / fmaxf(D0.z + D1.z + D2.z + D3.z, 1e-30f);
        x.w = (N0.w + N1.w + N2.w + N3.w) / fmaxf(D0.w + D1.w + D2.w + D3.w, 1e-30f);
        xsh4[t] = x;                   // xsh[h*32 + d4*4 + i]
    }
    __syncthreads();

    // ---- phase 3: out[b,q,:] = x @ wo + bo ----
    {
        const int j = t & 63, quarter = t >> 6;
        const float* xs = (const float*)xsh4;
        float p = 0.0f;
        #pragma unroll
        for (int c0 = 0; c0 < 64; ++c0) {
            const int c = quarter * 64 + c0;
            p += xs[c] * wo[c * NH + j];
        }
        psum[quarter][j] = p;
    }
    __syncthreads();
    if (t < NH) {
        out[bq_ * NH + t] = bo[t] + psum[0][t] + psum[1][t] + psum[2][t] + psum[3][t];
    }
}

extern "C" void kernel_launch(void* const* d_in, const int* in_sizes, int n_in,
                              void* d_out, int out_size, void* d_ws, size_t ws_size,
                              hipStream_t stream) {
    const float* qtt      = (const float*)d_in[0];
    const float* ktt      = (const float*)d_in[1];
    const float* value    = (const float*)d_in[2];
    const int*   emb_mask = (const int*)  d_in[3];
    const float* w_time   = (const float*)d_in[4];
    const float* b_time   = (const float*)d_in[5];
    const float* w_per    = (const float*)d_in[6];
    const float* b_per    = (const float*)d_in[7];
    const float* w_decay  = (const float*)d_in[8];
    const float* vt_w1    = (const float*)d_in[9];
    const float* vt_b1    = (const float*)d_in[10];
    const float* ln_g     = (const float*)d_in[11];
    const float* ln_b     = (const float*)d_in[12];
    const float* vt_w2    = (const float*)d_in[13];
    const float* vt_b2    = (const float*)d_in[14];
    const float* wq       = (const float*)d_in[15];
    const float* bq       = (const float*)d_in[16];
    const float* wk       = (const float*)d_in[17];
    const float* bk       = (const float*)d_in[18];
    const float* wo       = (const float*)d_in[19];
    const float* bo       = (const float*)d_in[20];
    float* out = (float*)d_out;

    float* ws  = (float*)d_ws;
    float* Aw  = ws;                 // 65536 floats
    float* Bw  = ws + 65536;         // 65536
    float* Mw  = ws + 131072;        // 65536
    float* qew = ws + 196608;        // 32768
    float* kew = ws + 229376;        // 65536

    hipLaunchKernelGGL(prep_kernel, dim3(896), dim3(256), 0, stream,
                       qtt, ktt, value, emb_mask, w_time, b_time, w_per, b_per,
                       vt_w1, vt_b1, ln_g, ln_b, vt_w2, vt_b2,
                       wq, bq, wk, bk, Aw, Bw, Mw, qew, kew);

    hipLaunchKernelGGL(attn_kernel, dim3(Bv_ * LQ), dim3(256), 0, stream,
                       qtt, ktt, w_decay, Aw, Bw, Mw, qew, kew, wo, bo, out);
}

// Round 3
// 114.632 us; speedup vs baseline: 1.2628x; 1.2628x over previous
//
#include <hip/hip_runtime.h>

#define Bv_ 8
#define LQ 128
#define LK 256
#define Dv 32
#define ET 32
#define Hh 8
#define NH 64
#define PADK 257   // Esh k-stride pad: h-stride 257 -> 8 distinct banks

// ---------------------------------------------------------------------------
// Kernel 1: prep  (896 blocks x 256 threads)  -- unchanged from round 2
// ---------------------------------------------------------------------------
__global__ __launch_bounds__(256) void prep_kernel(
    const float* __restrict__ qtt, const float* __restrict__ ktt,
    const float* __restrict__ value, const int* __restrict__ emb_mask,
    const float* __restrict__ w_time, const float* __restrict__ b_time,
    const float* __restrict__ w_per, const float* __restrict__ b_per,
    const float* __restrict__ vt_w1, const float* __restrict__ vt_b1,
    const float* __restrict__ ln_g, const float* __restrict__ ln_b,
    const float* __restrict__ vt_w2, const float* __restrict__ vt_b2,
    const float* __restrict__ wq, const float* __restrict__ bq,
    const float* __restrict__ wk, const float* __restrict__ bk,
    float* __restrict__ A, float* __restrict__ Bdv, float* __restrict__ mf,
    float* __restrict__ qe, float* __restrict__ ke)
{
    const int t = threadIdx.x;
    const int blk = blockIdx.x;

    if (blk < 512) {
        __shared__ float vrow[4][Dv];
        __shared__ float hrow[4][NH];
        const int w = t >> 6;
        const int l = t & 63;
        const int row = blk * 4 + w;

        if (l < Dv) vrow[w][l] = value[row * Dv + l];
        __syncthreads();

        float h = vt_b1[l];
        #pragma unroll
        for (int d = 0; d < Dv; ++d) h += vrow[w][d] * vt_w1[d * NH + l];

        float s = h;
        #pragma unroll
        for (int off = 32; off > 0; off >>= 1) s += __shfl_xor(s, off);
        const float mu = s * (1.0f / NH);
        const float dc = h - mu;
        float vs = dc * dc;
        #pragma unroll
        for (int off = 32; off > 0; off >>= 1) vs += __shfl_xor(vs, off);
        const float rs = rsqrtf(vs * (1.0f / NH) + 1e-5f);
        float hn = dc * rs * ln_g[l] + ln_b[l];
        hrow[w][l] = fmaxf(hn, 0.0f);
        __syncthreads();

        if (l < Dv) {
            float dval = vt_b2[l];
            #pragma unroll
            for (int j = 0; j < NH; ++j) dval += hrow[w][j] * vt_w2[j * Dv + l];
            const float mm = (emb_mask[row * Dv + l] != 0) ? 1.0f : 0.0f;
            A[row * Dv + l]   = mm * vrow[w][l];
            Bdv[row * Dv + l] = mm * dval;
            mf[row * Dv + l]  = mm;
        }
    } else {
        const int idx = blk - 512;
        const int sub = t >> 5;
        const int j = t & 31;
        const int row = idx * 8 + sub;
        __shared__ float eb[8][ET];

        float tt;
        const float *W, *bias;
        float* outp;
        if (row < Bv_ * LQ) {
            tt = qtt[row];
            W = wq; bias = bq; outp = qe + row * ET;
        } else {
            const int r2 = row - Bv_ * LQ;
            tt = ktt[r2];
            W = wk; bias = bk; outp = ke + r2 * ET;
        }
        float e;
        if (j == 0) e = tt * w_time[0] + b_time[0];
        else        e = __sinf(tt * w_per[j - 1] + b_per[j - 1]);
        eb[sub][j] = e;
        __syncthreads();

        float o = bias[j];
        #pragma unroll
        for (int i = 0; i < ET; ++i) o += eb[sub][i] * W[i * ET + j];
        outp[j] = o;
    }
}

// ---------------------------------------------------------------------------
// Kernel 2: attention. 256 blocks = (b, q-tile of 4). LDS-staged k-reduction.
//   LDS: As/Bs/Ms [256][32] (96KB), Esh[4][8][257] (~33KB), Gsh[4][256] (4KB)
//   main loop thread = (ks, h, d4): 4q x float4-d accumulators, no barriers.
//   psN/psD alias onto As after the main loop (32KB exactly).
// ---------------------------------------------------------------------------
__global__ __launch_bounds__(256, 1) void attn_kernel(
    const float* __restrict__ qtt, const float* __restrict__ ktt,
    const float* __restrict__ w_decay,
    const float* __restrict__ A, const float* __restrict__ Bdv,
    const float* __restrict__ mf,
    const float* __restrict__ qe, const float* __restrict__ ke,
    const float* __restrict__ wo, const float* __restrict__ bo,
    float* __restrict__ out)
{
    __shared__ float As[LK * Dv];          // 32KB (aliased by psN/psD later)
    __shared__ float Bs[LK * Dv];          // 32KB
    __shared__ float Ms[LK * Dv];          // 32KB
    __shared__ float Esh[4 * Hh * PADK];   // ~33KB
    __shared__ float Gsh[4 * LK];          // 4KB
    __shared__ float qrow_s[4 * ET];       // 0.5KB
    __shared__ float4 xsh4[4 * 64];        // 4KB

    const int t = threadIdx.x;
    const int blk = blockIdx.x;
    const int b = blk >> 5;
    const int q0 = (blk & 31) * 4;

    // ---- stage A/B/M panels for this b into LDS (coalesced float4) ----
    {
        const float4* Ag = (const float4*)(A   + (size_t)b * LK * Dv);
        const float4* Bg = (const float4*)(Bdv + (size_t)b * LK * Dv);
        const float4* Mg = (const float4*)(mf  + (size_t)b * LK * Dv);
        float4* As4 = (float4*)As;
        float4* Bs4 = (float4*)Bs;
        float4* Ms4 = (float4*)Ms;
        #pragma unroll
        for (int i = 0; i < 8; ++i) {
            const int idx = i * 256 + t;
            As4[idx] = Ag[idx];
            Bs4[idx] = Bg[idx];
            Ms4[idx] = Mg[idx];
        }
    }
    if (t < 4 * ET) qrow_s[t] = qe[((size_t)b * LQ + q0) * ET + t];
    __syncthreads();

    // ---- E phase: thread = k. E[q][h][k] and G[q][k] ----
    {
        const int k = t;
        const float4* kerow = (const float4*)(ke + ((size_t)b * LK + k) * ET);
        float4 kreg[Hh];
        #pragma unroll
        for (int h = 0; h < Hh; ++h) kreg[h] = kerow[h];
        const float ktime = ktt[b * LK + k];
        const float wd = w_decay[0];
        #pragma unroll
        for (int q = 0; q < 4; ++q) {
            const float dt = qtt[b * LQ + q0 + q] - ktime;
            Gsh[q * LK + k] = dt / fmaf(wd, dt, 1.0f);
            const float4* qq4 = (const float4*)(qrow_s + q * ET);
            #pragma unroll
            for (int h = 0; h < Hh; ++h) {
                const float4 qq = qq4[h];
                const float4 kv = kreg[h];
                const float sc = 0.5f * (qq.x * kv.x + qq.y * kv.y +
                                         qq.z * kv.z + qq.w * kv.w);
                Esh[(q * Hh + h) * PADK + k] = __expf(sc);  // |sc| << 1
            }
        }
    }
    __syncthreads();

    // ---- main k-loop: thread = (ks, h, d4); all reads from LDS ----
    const int ks = t >> 6;
    const int h  = (t >> 3) & 7;
    const int d4 = t & 7;
    float4 accN[4], accD[4];
    #pragma unroll
    for (int q = 0; q < 4; ++q) {
        accN[q] = make_float4(0.f, 0.f, 0.f, 0.f);
        accD[q] = make_float4(0.f, 0.f, 0.f, 0.f);
    }
    {
        const float4* As4 = (const float4*)As;
        const float4* Bs4 = (const float4*)Bs;
        const float4* Ms4 = (const float4*)Ms;
        const float* Eh0 = Esh + h * PADK;
        const int k0 = ks * 64;
        #pragma unroll 4
        for (int kk_ = 0; kk_ < 64; ++kk_) {
            const int k = k0 + kk_;
            const float4 a  = As4[k * 8 + d4];
            const float4 bb = Bs4[k * 8 + d4];
            const float4 m  = Ms4[k * 8 + d4];
            #pragma unroll
            for (int q = 0; q < 4; ++q) {
                const float e  = Eh0[q * (Hh * PADK) + k];
                const float eg = e * Gsh[q * LK + k];
                accN[q].x = fmaf(e, a.x, fmaf(eg, bb.x, accN[q].x));
                accN[q].y = fmaf(e, a.y, fmaf(eg, bb.y, accN[q].y));
                accN[q].z = fmaf(e, a.z, fmaf(eg, bb.z, accN[q].z));
                accN[q].w = fmaf(e, a.w, fmaf(eg, bb.w, accN[q].w));
                accD[q].x = fmaf(e, m.x, accD[q].x);
                accD[q].y = fmaf(e, m.y, accD[q].y);
                accD[q].z = fmaf(e, m.z, accD[q].z);
                accD[q].w = fmaf(e, m.w, accD[q].w);
            }
        }
    }
    __syncthreads();

    // ---- write per-ks partials into the As region (alias, 32KB exactly) ----
    {
        float4* psN = (float4*)As;          // [ks*4+q][64]  (1024 float4)
        float4* psD = ((float4*)As) + 1024; // next 1024 float4
        const int cls = t & 63;
        #pragma unroll
        for (int q = 0; q < 4; ++q) {
            psN[(ks * 4 + q) * 64 + cls] = accN[q];
            psD[(ks * 4 + q) * 64 + cls] = accD[q];
        }
    }
    __syncthreads();

    // ---- cross-ks reduce + divide: thread = (q, cls) ----
    {
        const int q = t >> 6, cls = t & 63;
        const float4* psN = (const float4*)As;
        const float4* psD = ((const float4*)As) + 1024;
        float4 n = make_float4(0.f, 0.f, 0.f, 0.f);
        float4 d = make_float4(0.f, 0.f, 0.f, 0.f);
        #pragma unroll
        for (int s = 0; s < 4; ++s) {
            const float4 nn = psN[(s * 4 + q) * 64 + cls];
            const float4 dd = psD[(s * 4 + q) * 64 + cls];
            n.x += nn.x; n.y += nn.y; n.z += nn.z; n.w += nn.w;
            d.x += dd.x; d.y += dd.y; d.z += dd.z; d.w += dd.w;
        }
        float4 x;
        x.x = n.x / fmaxf(d.x, 1e-30f);
        x.y = n.y / fmaxf(d.y, 1e-30f);
        x.z = n.z / fmaxf(d.z, 1e-30f);
        x.w = n.w / fmaxf(d.w, 1e-30f);
        xsh4[q * 64 + cls] = x;            // x[q][h*32+d] as float4
    }
    __syncthreads();

    // ---- epilogue: out[b,q0+q,:] = x @ wo + bo. thread = (q, j) ----
    {
        const int q = t >> 6, j = t & 63;
        float acc = bo[j];
        #pragma unroll 8
        for (int c4 = 0; c4 < 64; ++c4) {
            const float4 xv = xsh4[q * 64 + c4];
            const int c = c4 * 4;
            acc = fmaf(xv.x, wo[(c + 0) * NH + j], acc);
            acc = fmaf(xv.y, wo[(c + 1) * NH + j], acc);
            acc = fmaf(xv.z, wo[(c + 2) * NH + j], acc);
            acc = fmaf(xv.w, wo[(c + 3) * NH + j], acc);
        }
        out[((size_t)b * LQ + q0 + q) * NH + j] = acc;
    }
}

extern "C" void kernel_launch(void* const* d_in, const int* in_sizes, int n_in,
                              void* d_out, int out_size, void* d_ws, size_t ws_size,
                              hipStream_t stream) {
    const float* qtt      = (const float*)d_in[0];
    const float* ktt      = (const float*)d_in[1];
    const float* value    = (const float*)d_in[2];
    const int*   emb_mask = (const int*)  d_in[3];
    const float* w_time   = (const float*)d_in[4];
    const float* b_time   = (const float*)d_in[5];
    const float* w_per    = (const float*)d_in[6];
    const float* b_per    = (const float*)d_in[7];
    const float* w_decay  = (const float*)d_in[8];
    const float* vt_w1    = (const float*)d_in[9];
    const float* vt_b1    = (const float*)d_in[10];
    const float* ln_g     = (const float*)d_in[11];
    const float* ln_b     = (const float*)d_in[12];
    const float* vt_w2    = (const float*)d_in[13];
    const float* vt_b2    = (const float*)d_in[14];
    const float* wq       = (const float*)d_in[15];
    const float* bq       = (const float*)d_in[16];
    const float* wk       = (const float*)d_in[17];
    const float* bk       = (const float*)d_in[18];
    const float* wo       = (const float*)d_in[19];
    const float* bo       = (const float*)d_in[20];
    float* out = (float*)d_out;

    float* ws  = (float*)d_ws;
    float* Aw  = ws;                 // 65536 floats
    float* Bw  = ws + 65536;         // 65536
    float* Mw  = ws + 131072;        // 65536
    float* qew = ws + 196608;        // 32768
    float* kew = ws + 229376;        // 65536

    hipLaunchKernelGGL(prep_kernel, dim3(896), dim3(256), 0, stream,
                       qtt, ktt, value, emb_mask, w_time, b_time, w_per, b_per,
                       vt_w1, vt_b1, ln_g, ln_b, vt_w2, vt_b2,
                       wq, bq, wk, bk, Aw, Bw, Mw, qew, kew);

    hipLaunchKernelGGL(attn_kernel, dim3(256), dim3(256), 0, stream,
                       qtt, ktt, w_decay, Aw, Bw, Mw, qew, kew, wo, bo, out);
}

// Round 7
// 112.683 us; speedup vs baseline: 1.2847x; 1.0173x over previous
//
#include <hip/hip_runtime.h>

#define Bv_ 8
#define LQ 128
#define LK 256
#define Dv 32
#define ET 32
#define Hh 8
#define NH 64

// Exact type returned by __builtin_amdgcn_cvt_pkrtz on this toolchain.
typedef __fp16 h2 __attribute__((ext_vector_type(2)));

static __device__ __forceinline__ h2 bch(unsigned u) {
    union { unsigned u; h2 h; } c; c.u = u; return c.h;
}
static __device__ __forceinline__ unsigned pack2(float lo, float hi) {
    union { h2 h; unsigned u; } c;
    c.h = __builtin_amdgcn_cvt_pkrtz(lo, hi);
    return c.u;
}
static __device__ __forceinline__ unsigned short h16(float x) {
    union { __fp16 h; unsigned short u; } c; c.h = (__fp16)x; return c.u;
}
static __device__ __forceinline__ float dot2(h2 a, h2 b, float c) {
#if __has_builtin(__builtin_amdgcn_fdot2)
    return __builtin_amdgcn_fdot2(a, b, c, false);
#else
    return fmaf((float)a.x, (float)b.x, fmaf((float)a.y, (float)b.y, c));
#endif
}

// ---------------------------------------------------------------------------
// Kernel 1: prep (896 blocks x 256)
//  blocks [0,512): 4 value-MLP rows/block -> packed f16 A2/B2/M2 (k-pairs)
//  blocks [512,896): 8 time-embedding rows/block -> qe, ke (f32)
// ---------------------------------------------------------------------------
__global__ __launch_bounds__(256) void prep_kernel(
    const float* __restrict__ qtt, const float* __restrict__ ktt,
    const float* __restrict__ value, const int* __restrict__ emb_mask,
    const float* __restrict__ w_time, const float* __restrict__ b_time,
    const float* __restrict__ w_per, const float* __restrict__ b_per,
    const float* __restrict__ vt_w1, const float* __restrict__ vt_b1,
    const float* __restrict__ ln_g, const float* __restrict__ ln_b,
    const float* __restrict__ vt_w2, const float* __restrict__ vt_b2,
    const float* __restrict__ wq, const float* __restrict__ bq,
    const float* __restrict__ wk, const float* __restrict__ bk,
    unsigned* __restrict__ A2g, unsigned* __restrict__ B2g,
    unsigned* __restrict__ M2g,
    float* __restrict__ qe, float* __restrict__ ke)
{
    const int t = threadIdx.x;
    const int blk = blockIdx.x;

    if (blk < 512) {
        __shared__ float vrow[4][Dv];
        __shared__ float hrow[4][NH];
        __shared__ float sha[4][Dv], shb[4][Dv], shm[4][Dv];
        const int w = t >> 6;
        const int l = t & 63;
        const int row = blk * 4 + w;           // global (b,k) row

        if (l < Dv) vrow[w][l] = value[row * Dv + l];
        __syncthreads();

        float h = vt_b1[l];
        #pragma unroll
        for (int d = 0; d < Dv; ++d) h += vrow[w][d] * vt_w1[d * NH + l];

        float s = h;
        #pragma unroll
        for (int off = 32; off > 0; off >>= 1) s += __shfl_xor(s, off);
        const float mu = s * (1.0f / NH);
        const float dc = h - mu;
        float vs = dc * dc;
        #pragma unroll
        for (int off = 32; off > 0; off >>= 1) vs += __shfl_xor(vs, off);
        const float rs = rsqrtf(vs * (1.0f / NH) + 1e-5f);
        hrow[w][l] = fmaxf(dc * rs * ln_g[l] + ln_b[l], 0.0f);
        __syncthreads();

        if (l < Dv) {
            float dval = vt_b2[l];
            #pragma unroll
            for (int j = 0; j < NH; ++j) dval += hrow[w][j] * vt_w2[j * Dv + l];
            const float mm = (emb_mask[row * Dv + l] != 0) ? 1.0f : 0.0f;
            sha[w][l] = mm * vrow[w][l];
            shb[w][l] = mm * dval;
            shm[w][l] = mm;
        }
        __syncthreads();

        if (t < 192) {                         // pack k-pairs -> f16x2
            const int arr = t >> 6;            // wave-uniform
            const int pr  = (t >> 5) & 1;
            const int d   = t & 31;
            float lo, hi;
            unsigned* dst;
            if (arr == 0)      { lo = sha[2*pr][d]; hi = sha[2*pr+1][d]; dst = A2g; }
            else if (arr == 1) { lo = shb[2*pr][d]; hi = shb[2*pr+1][d]; dst = B2g; }
            else               { lo = shm[2*pr][d]; hi = shm[2*pr+1][d]; dst = M2g; }
            dst[(blk * 2 + pr) * 32 + d] = pack2(lo, hi);
        }
    } else {
        const int idx = blk - 512;
        const int sub = t >> 5;
        const int j = t & 31;
        const int row = idx * 8 + sub;         // 0..3071
        __shared__ float eb[8][ET];

        float tt;
        const float *W, *bias;
        float* outp;
        if (row < Bv_ * LQ) {
            tt = qtt[row]; W = wq; bias = bq; outp = qe + row * ET;
        } else {
            const int r2 = row - Bv_ * LQ;
            tt = ktt[r2]; W = wk; bias = bk; outp = ke + r2 * ET;
        }
        float e;
        if (j == 0) e = tt * w_time[0] + b_time[0];
        else        e = __sinf(tt * w_per[j - 1] + b_per[j - 1]);
        eb[sub][j] = e;
        __syncthreads();

        float o = bias[j];
        #pragma unroll
        for (int i = 0; i < ET; ++i) o += eb[sub][i] * W[i * ET + j];
        outp[j] = o;
    }
}

// ---------------------------------------------------------------------------
// Kernel 2: attention. 256 blocks = (b, q-tile of 4). f16-dot2 main loop.
// LDS carve (uint units):
//   A2s 0..4095 | B2s 4096..8191 | M2s 8192..12287
//   kes (f32, row stride 37) 12288..21759  (256*37 = 9472 f)
//   E2s 21760..25983 ([32][132] u)  | EG2s 25984..30207 ([32][132] u)
//   qrs 30208..30335 (128 f) | XSH 30336..31359 (1024 f) | qts 31360..31363
// Aliases after main loop: REDN = kes region (>=8192f), REDD = LDSu+0 (8192f).
// ---------------------------------------------------------------------------
__global__ __launch_bounds__(256, 1) void attn_kernel(
    const float* __restrict__ qtt, const float* __restrict__ ktt,
    const float* __restrict__ w_decay,
    const unsigned* __restrict__ A2g, const unsigned* __restrict__ B2g,
    const unsigned* __restrict__ M2g,
    const float* __restrict__ qe, const float* __restrict__ ke,
    const float* __restrict__ wo, const float* __restrict__ bo,
    float* __restrict__ out)
{
    __shared__ __align__(16) unsigned LDSu[31364];
    unsigned* A2s = LDSu;
    unsigned* B2s = LDSu + 4096;
    unsigned* M2s = LDSu + 8192;
    float*    kes = (float*)(LDSu + 12288);   // [256][37]
    unsigned* E2s  = LDSu + 21760;            // [32][132]
    unsigned* EG2s = LDSu + 25984;            // [32][132]
    float*    qrs = (float*)(LDSu + 30208);   // [4][32], pre-scaled by 0.5
    float*    XSH = (float*)(LDSu + 30336);   // [1024]
    float*    qts = (float*)(LDSu + 31360);   // [4]

    const int t = threadIdx.x;
    const int blk = blockIdx.x;
    const int b = blk >> 5;
    const int q0 = (blk & 31) * 4;

    // ---- stage packed panels + ke + q-row ----
    {
        const uint4* Ag = (const uint4*)(A2g + (size_t)b * 4096);
        const uint4* Bg = (const uint4*)(B2g + (size_t)b * 4096);
        const uint4* Mg = (const uint4*)(M2g + (size_t)b * 4096);
        #pragma unroll
        for (int i = 0; i < 4; ++i) {
            const int idx = i * 256 + t;
            ((uint4*)A2s)[idx] = Ag[idx];
            ((uint4*)B2s)[idx] = Bg[idx];
            ((uint4*)M2s)[idx] = Mg[idx];
        }
        const float4* keg = (const float4*)(ke + (size_t)b * LK * ET);
        #pragma unroll
        for (int i = 0; i < 8; ++i) {
            const int idx = i * 256 + t;
            const int row = idx >> 3, c = idx & 7;
            *(float4*)&kes[row * 37 + c * 4] = keg[idx];
        }
        if (t < 128) qrs[t] = 0.5f * qe[((size_t)b * LQ + q0) * ET + t];
        if (t < 4)   qts[t] = qtt[b * LQ + q0 + t];
    }
    __syncthreads();

    // ---- E/EG phase: thread = k ----
    {
        const float ktk = ktt[b * LK + t];
        const float wd = w_decay[0];
        unsigned short* E2u  = (unsigned short*)E2s;    // row stride 264 u16
        unsigned short* EG2u = (unsigned short*)EG2s;
        float4 kr[8];
        #pragma unroll
        for (int h = 0; h < 8; ++h) kr[h] = *(const float4*)&kes[t * 37 + h * 4];
        #pragma unroll
        for (int q = 0; q < 4; ++q) {
            const float dt = qts[q] - ktk;
            const float g = dt / fmaf(wd, dt, 1.0f);
            #pragma unroll
            for (int h = 0; h < 8; ++h) {
                const float4 qq = *(const float4*)&qrs[q * 32 + h * 4];
                float sc = qq.x * kr[h].x;
                sc = fmaf(qq.y, kr[h].y, sc);
                sc = fmaf(qq.z, kr[h].z, sc);
                sc = fmaf(qq.w, kr[h].w, sc);
                const float e = __expf(sc);       // |sc| << 1
                E2u[(q * 8 + h) * 264 + t]  = h16(e);
                EG2u[(q * 8 + h) * 264 + t] = h16(e * g);
            }
        }
    }
    __syncthreads();

    // ---- main loop: thread = (ks 0..7, hg 0..3 -> h{2hg,2hg+1}, dg 0..7) ----
    const int ks = t >> 5, hg = (t >> 3) & 3, dg = t & 7;
    const int hb = 2 * hg;
    float accN[4][2][4] = {{{0}}}, accD[4][2][4] = {{{0}}};
    {
        const unsigned* Eb  = E2s  + ks * 16;
        const unsigned* EGb = EG2s + ks * 16;
        const unsigned* Ab = A2s + ks * 512 + dg * 4;
        const unsigned* Bb = B2s + ks * 512 + dg * 4;
        const unsigned* Mb = M2s + ks * 512 + dg * 4;
        #pragma unroll
        for (int si = 0; si < 4; ++si) {
            unsigned eu[4][2][4], egu[4][2][4];
            unsigned au[4][4], bu[4][4], mu_[4][4];
            #pragma unroll
            for (int q = 0; q < 4; ++q) {
                #pragma unroll
                for (int hh = 0; hh < 2; ++hh) {
                    const uint4 v = *(const uint4*)(Eb  + (q*8 + hb + hh)*132 + si*4);
                    const uint4 w = *(const uint4*)(EGb + (q*8 + hb + hh)*132 + si*4);
                    eu[q][hh][0]=v.x; eu[q][hh][1]=v.y; eu[q][hh][2]=v.z; eu[q][hh][3]=v.w;
                    egu[q][hh][0]=w.x; egu[q][hh][1]=w.y; egu[q][hh][2]=w.z; egu[q][hh][3]=w.w;
                }
            }
            #pragma unroll
            for (int j = 0; j < 4; ++j) {
                const uint4 a  = *(const uint4*)(Ab + (si*4 + j)*32);
                const uint4 bb = *(const uint4*)(Bb + (si*4 + j)*32);
                const uint4 m  = *(const uint4*)(Mb + (si*4 + j)*32);
                au[j][0]=a.x; au[j][1]=a.y; au[j][2]=a.z; au[j][3]=a.w;
                bu[j][0]=bb.x; bu[j][1]=bb.y; bu[j][2]=bb.z; bu[j][3]=bb.w;
                mu_[j][0]=m.x; mu_[j][1]=m.y; mu_[j][2]=m.z; mu_[j][3]=m.w;
            }
            #pragma unroll
            for (int q = 0; q < 4; ++q)
            #pragma unroll
            for (int hh = 0; hh < 2; ++hh)
            #pragma unroll
            for (int j = 0; j < 4; ++j) {
                const h2 e2  = bch(eu[q][hh][j]);
                const h2 eg2 = bch(egu[q][hh][j]);
                #pragma unroll
                for (int dd = 0; dd < 4; ++dd) {
                    accN[q][hh][dd] = dot2(e2,  bch(au[j][dd]),  accN[q][hh][dd]);
                    accN[q][hh][dd] = dot2(eg2, bch(bu[j][dd]),  accN[q][hh][dd]);
                    accD[q][hh][dd] = dot2(e2,  bch(mu_[j][dd]), accD[q][hh][dd]);
                }
            }
        }
    }
    __syncthreads();

    // ---- cross-ks partials (alias over dead panels) ----
    float* REDN = kes;            // >= 8192 f
    float* REDD = (float*)LDSu;   // 8192 f (A2s+B2s region)
    #pragma unroll
    for (int q = 0; q < 4; ++q)
    #pragma unroll
    for (int hh = 0; hh < 2; ++hh) {
        const int c = (q * 8 + hb + hh) * 32 + dg * 4;
        *(float4*)&REDN[ks * 1024 + c] =
            make_float4(accN[q][hh][0], accN[q][hh][1], accN[q][hh][2], accN[q][hh][3]);
        *(float4*)&REDD[ks * 1024 + c] =
            make_float4(accD[q][hh][0], accD[q][hh][1], accD[q][hh][2], accD[q][hh][3]);
    }
    __syncthreads();

    // ---- reduce over ks + divide ----
    {
        float4 n = make_float4(0.f,0.f,0.f,0.f), d = make_float4(0.f,0.f,0.f,0.f);
        #pragma unroll
        for (int s = 0; s < 8; ++s) {
            const float4 nn = *(const float4*)&REDN[s * 1024 + t * 4];
            const float4 dd = *(const float4*)&REDD[s * 1024 + t * 4];
            n.x += nn.x; n.y += nn.y; n.z += nn.z; n.w += nn.w;
            d.x += dd.x; d.y += dd.y; d.z += dd.z; d.w += dd.w;
        }
        float4 x;
        x.x = n.x / fmaxf(d.x, 1e-30f);
        x.y = n.y / fmaxf(d.y, 1e-30f);
        x.z = n.z / fmaxf(d.z, 1e-30f);
        x.w = n.w / fmaxf(d.w, 1e-30f);
        *(float4*)&XSH[t * 4] = x;
    }
    __syncthreads();

    // ---- epilogue: out = x @ wo + bo. thread = (q, j) ----
    {
        const int q = t >> 6, j = t & 63;
        float acc = bo[j];
        const float4* xq = (const float4*)&XSH[q * 256];
        #pragma unroll 8
        for (int c4 = 0; c4 < 64; ++c4) {
            const float4 xv = xq[c4];
            const int c = c4 * 4;
            acc = fmaf(xv.x, wo[(c + 0) * NH + j], acc);
            acc = fmaf(xv.y, wo[(c + 1) * NH + j], acc);
            acc = fmaf(xv.z, wo[(c + 2) * NH + j], acc);
            acc = fmaf(xv.w, wo[(c + 3) * NH + j], acc);
        }
        out[((size_t)b * LQ + q0 + q) * NH + j] = acc;
    }
}

extern "C" void kernel_launch(void* const* d_in, const int* in_sizes, int n_in,
                              void* d_out, int out_size, void* d_ws, size_t ws_size,
                              hipStream_t stream) {
    const float* qtt      = (const float*)d_in[0];
    const float* ktt      = (const float*)d_in[1];
    const float* value    = (const float*)d_in[2];
    const int*   emb_mask = (const int*)  d_in[3];
    const float* w_time   = (const float*)d_in[4];
    const float* b_time   = (const float*)d_in[5];
    const float* w_per    = (const float*)d_in[6];
    const float* b_per    = (const float*)d_in[7];
    const float* w_decay  = (const float*)d_in[8];
    const float* vt_w1    = (const float*)d_in[9];
    const float* vt_b1    = (const float*)d_in[10];
    const float* ln_g     = (const float*)d_in[11];
    const float* ln_b     = (const float*)d_in[12];
    const float* vt_w2    = (const float*)d_in[13];
    const float* vt_b2    = (const float*)d_in[14];
    const float* wq       = (const float*)d_in[15];
    const float* bq       = (const float*)d_in[16];
    const float* wk       = (const float*)d_in[17];
    const float* bk       = (const float*)d_in[18];
    const float* wo       = (const float*)d_in[19];
    const float* bo       = (const float*)d_in[20];
    float* out = (float*)d_out;

    unsigned* wsu = (unsigned*)d_ws;
    unsigned* A2g = wsu;               // 32768 u (1024 k2 x 32 d)
    unsigned* B2g = wsu + 32768;
    unsigned* M2g = wsu + 65536;
    float*    qew = (float*)(wsu + 98304);   // 32768 f
    float*    kew = (float*)(wsu + 131072);  // 65536 f

    hipLaunchKernelGGL(prep_kernel, dim3(896), dim3(256), 0, stream,
                       qtt, ktt, value, emb_mask, w_time, b_time, w_per, b_per,
                       vt_w1, vt_b1, ln_g, ln_b, vt_w2, vt_b2,
                       wq, bq, wk, bk, A2g, B2g, M2g, qew, kew);

    hipLaunchKernelGGL(attn_kernel, dim3(256), dim3(256), 0, stream,
                       qtt, ktt, w_decay, A2g, B2g, M2g, qew, kew, wo, bo, out);
}

// Round 8
// 110.671 us; speedup vs baseline: 1.3080x; 1.0182x over previous
//
#include <hip/hip_runtime.h>

#define Bv_ 8
#define LQ 128
#define LK 256
#define Dv 32
#define ET 32
#define Hh 8
#define NH 64

// Exact type returned by __builtin_amdgcn_cvt_pkrtz on this toolchain.
typedef __fp16 h2 __attribute__((ext_vector_type(2)));

static __device__ __forceinline__ h2 bch(unsigned u) {
    union { unsigned u; h2 h; } c; c.u = u; return c.h;
}
static __device__ __forceinline__ unsigned pack2(float lo, float hi) {
    union { h2 h; unsigned u; } c;
    c.h = __builtin_amdgcn_cvt_pkrtz(lo, hi);
    return c.u;
}
static __device__ __forceinline__ unsigned short h16(float x) {
    union { __fp16 h; unsigned short u; } c; c.h = (__fp16)x; return c.u;
}
static __device__ __forceinline__ float dot2(h2 a, h2 b, float c) {
#if __has_builtin(__builtin_amdgcn_fdot2)
    return __builtin_amdgcn_fdot2(a, b, c, false);
#else
    return fmaf((float)a.x, (float)b.x, fmaf((float)a.y, (float)b.y, c));
#endif
}

// ---------------------------------------------------------------------------
// Kernel 1: prep (896 blocks x 256) -- unchanged from R7
// ---------------------------------------------------------------------------
__global__ __launch_bounds__(256) void prep_kernel(
    const float* __restrict__ qtt, const float* __restrict__ ktt,
    const float* __restrict__ value, const int* __restrict__ emb_mask,
    const float* __restrict__ w_time, const float* __restrict__ b_time,
    const float* __restrict__ w_per, const float* __restrict__ b_per,
    const float* __restrict__ vt_w1, const float* __restrict__ vt_b1,
    const float* __restrict__ ln_g, const float* __restrict__ ln_b,
    const float* __restrict__ vt_w2, const float* __restrict__ vt_b2,
    const float* __restrict__ wq, const float* __restrict__ bq,
    const float* __restrict__ wk, const float* __restrict__ bk,
    unsigned* __restrict__ A2g, unsigned* __restrict__ B2g,
    unsigned* __restrict__ M2g,
    float* __restrict__ qe, float* __restrict__ ke)
{
    const int t = threadIdx.x;
    const int blk = blockIdx.x;

    if (blk < 512) {
        __shared__ float vrow[4][Dv];
        __shared__ float hrow[4][NH];
        __shared__ float sha[4][Dv], shb[4][Dv], shm[4][Dv];
        const int w = t >> 6;
        const int l = t & 63;
        const int row = blk * 4 + w;           // global (b,k) row

        if (l < Dv) vrow[w][l] = value[row * Dv + l];
        __syncthreads();

        float h = vt_b1[l];
        #pragma unroll
        for (int d = 0; d < Dv; ++d) h += vrow[w][d] * vt_w1[d * NH + l];

        float s = h;
        #pragma unroll
        for (int off = 32; off > 0; off >>= 1) s += __shfl_xor(s, off);
        const float mu = s * (1.0f / NH);
        const float dc = h - mu;
        float vs = dc * dc;
        #pragma unroll
        for (int off = 32; off > 0; off >>= 1) vs += __shfl_xor(vs, off);
        const float rs = rsqrtf(vs * (1.0f / NH) + 1e-5f);
        hrow[w][l] = fmaxf(dc * rs * ln_g[l] + ln_b[l], 0.0f);
        __syncthreads();

        if (l < Dv) {
            float dval = vt_b2[l];
            #pragma unroll
            for (int j = 0; j < NH; ++j) dval += hrow[w][j] * vt_w2[j * Dv + l];
            const float mm = (emb_mask[row * Dv + l] != 0) ? 1.0f : 0.0f;
            sha[w][l] = mm * vrow[w][l];
            shb[w][l] = mm * dval;
            shm[w][l] = mm;
        }
        __syncthreads();

        if (t < 192) {                         // pack k-pairs -> f16x2
            const int arr = t >> 6;            // wave-uniform
            const int pr  = (t >> 5) & 1;
            const int d   = t & 31;
            float lo, hi;
            unsigned* dst;
            if (arr == 0)      { lo = sha[2*pr][d]; hi = sha[2*pr+1][d]; dst = A2g; }
            else if (arr == 1) { lo = shb[2*pr][d]; hi = shb[2*pr+1][d]; dst = B2g; }
            else               { lo = shm[2*pr][d]; hi = shm[2*pr+1][d]; dst = M2g; }
            dst[(blk * 2 + pr) * 32 + d] = pack2(lo, hi);
        }
    } else {
        const int idx = blk - 512;
        const int sub = t >> 5;
        const int j = t & 31;
        const int row = idx * 8 + sub;         // 0..3071
        __shared__ float eb[8][ET];

        float tt;
        const float *W, *bias;
        float* outp;
        if (row < Bv_ * LQ) {
            tt = qtt[row]; W = wq; bias = bq; outp = qe + row * ET;
        } else {
            const int r2 = row - Bv_ * LQ;
            tt = ktt[r2]; W = wk; bias = bk; outp = ke + r2 * ET;
        }
        float e;
        if (j == 0) e = tt * w_time[0] + b_time[0];
        else        e = __sinf(tt * w_per[j - 1] + b_per[j - 1]);
        eb[sub][j] = e;
        __syncthreads();

        float o = bias[j];
        #pragma unroll
        for (int i = 0; i < ET; ++i) o += eb[sub][i] * W[i * ET + j];
        outp[j] = o;
    }
}

// ---------------------------------------------------------------------------
// Kernel 2: attention. 512 blocks = (b, q-tile of 2). 2 blocks/CU.
// LDS carve (uint units), total 17090 u = 68.4 KB:
//   A2s 0..4095 | B2s 4096..8191 | M2s 8192..12287
//   E2s 12288..14399 ([16][132])  | EG2s 14400..16511 ([16][132])
//   qrs 16512..16575 (64 f) | XSH 16576..17087 (512 f) | qts 17088..17089
// Aliases after main loop: REDN = A2s (4096 f), REDD = B2s (4096 f).
// ---------------------------------------------------------------------------
__global__ __launch_bounds__(256, 2) void attn_kernel(
    const float* __restrict__ qtt, const float* __restrict__ ktt,
    const float* __restrict__ w_decay,
    const unsigned* __restrict__ A2g, const unsigned* __restrict__ B2g,
    const unsigned* __restrict__ M2g,
    const float* __restrict__ qe, const float* __restrict__ ke,
    const float* __restrict__ wo, const float* __restrict__ bo,
    float* __restrict__ out)
{
    __shared__ __align__(16) unsigned LDSu[17090];
    unsigned* A2s  = LDSu;
    unsigned* B2s  = LDSu + 4096;
    unsigned* M2s  = LDSu + 8192;
    unsigned* E2s  = LDSu + 12288;            // [16][132]
    unsigned* EG2s = LDSu + 14400;            // [16][132]
    float*    qrs  = (float*)(LDSu + 16512);  // [2][32], pre-scaled by 0.5
    float*    XSH  = (float*)(LDSu + 16576);  // [512]
    float*    qts  = (float*)(LDSu + 17088);  // [2]

    const int t = threadIdx.x;
    const int blk = blockIdx.x;
    const int b = blk >> 6;
    const int q0 = (blk & 63) * 2;

    // ---- stage packed panels (coalesced uint4) + q row ----
    {
        const uint4* Ag = (const uint4*)(A2g + (size_t)b * 4096);
        const uint4* Bg = (const uint4*)(B2g + (size_t)b * 4096);
        const uint4* Mg = (const uint4*)(M2g + (size_t)b * 4096);
        #pragma unroll
        for (int i = 0; i < 4; ++i) {
            const int idx = i * 256 + t;
            ((uint4*)A2s)[idx] = Ag[idx];
            ((uint4*)B2s)[idx] = Bg[idx];
            ((uint4*)M2s)[idx] = Mg[idx];
        }
        if (t < 64) qrs[t] = 0.5f * qe[((size_t)b * LQ + q0) * ET + t];
        if (t < 2)  qts[t] = qtt[b * LQ + q0 + t];
    }
    __syncthreads();

    // ---- E/EG phase: thread = k; ke read directly from global (L2-hot) ----
    {
        const int k = t;
        const float4* kerow = (const float4*)(ke + ((size_t)b * LK + k) * ET);
        float4 kr[8];
        #pragma unroll
        for (int h = 0; h < 8; ++h) kr[h] = kerow[h];
        const float ktk = ktt[b * LK + k];
        const float wd = w_decay[0];
        unsigned short* E2u  = (unsigned short*)E2s;    // row stride 264 u16
        unsigned short* EG2u = (unsigned short*)EG2s;
        #pragma unroll
        for (int q = 0; q < 2; ++q) {
            const float dt = qts[q] - ktk;
            const float g = dt / fmaf(wd, dt, 1.0f);
            #pragma unroll
            for (int h = 0; h < 8; ++h) {
                const float4 qq = *(const float4*)&qrs[q * 32 + h * 4];
                float sc = qq.x * kr[h].x;
                sc = fmaf(qq.y, kr[h].y, sc);
                sc = fmaf(qq.z, kr[h].z, sc);
                sc = fmaf(qq.w, kr[h].w, sc);
                const float e = __expf(sc);       // |sc| << 1
                E2u[(q * 8 + h) * 264 + k]  = h16(e);
                EG2u[(q * 8 + h) * 264 + k] = h16(e * g);
            }
        }
    }
    __syncthreads();

    // ---- main loop: thread = (ks 0..7, hg 0..3 -> h{2hg,2hg+1}, dg 0..7) ----
    const int ks = t >> 5, hg = (t >> 3) & 3, dg = t & 7;
    const int hb = 2 * hg;
    float accN[2][2][4] = {{{0}}}, accD[2][2][4] = {{{0}}};
    {
        const unsigned* Eb  = E2s  + ks * 16;
        const unsigned* EGb = EG2s + ks * 16;
        const unsigned* Ab = A2s + ks * 512 + dg * 4;
        const unsigned* Bb = B2s + ks * 512 + dg * 4;
        const unsigned* Mb = M2s + ks * 512 + dg * 4;
        #pragma unroll
        for (int si = 0; si < 4; ++si) {
            unsigned eu[2][2][4], egu[2][2][4];
            unsigned au[4][4], bu[4][4], mu_[4][4];
            #pragma unroll
            for (int q = 0; q < 2; ++q) {
                #pragma unroll
                for (int hh = 0; hh < 2; ++hh) {
                    const uint4 v = *(const uint4*)(Eb  + (q*8 + hb + hh)*132 + si*4);
                    const uint4 w = *(const uint4*)(EGb + (q*8 + hb + hh)*132 + si*4);
                    eu[q][hh][0]=v.x; eu[q][hh][1]=v.y; eu[q][hh][2]=v.z; eu[q][hh][3]=v.w;
                    egu[q][hh][0]=w.x; egu[q][hh][1]=w.y; egu[q][hh][2]=w.z; egu[q][hh][3]=w.w;
                }
            }
            #pragma unroll
            for (int j = 0; j < 4; ++j) {
                const uint4 a  = *(const uint4*)(Ab + (si*4 + j)*32);
                const uint4 bb = *(const uint4*)(Bb + (si*4 + j)*32);
                const uint4 m  = *(const uint4*)(Mb + (si*4 + j)*32);
                au[j][0]=a.x; au[j][1]=a.y; au[j][2]=a.z; au[j][3]=a.w;
                bu[j][0]=bb.x; bu[j][1]=bb.y; bu[j][2]=bb.z; bu[j][3]=bb.w;
                mu_[j][0]=m.x; mu_[j][1]=m.y; mu_[j][2]=m.z; mu_[j][3]=m.w;
            }
            #pragma unroll
            for (int q = 0; q < 2; ++q)
            #pragma unroll
            for (int hh = 0; hh < 2; ++hh)
            #pragma unroll
            for (int j = 0; j < 4; ++j) {
                const h2 e2  = bch(eu[q][hh][j]);
                const h2 eg2 = bch(egu[q][hh][j]);
                #pragma unroll
                for (int dd = 0; dd < 4; ++dd) {
                    accN[q][hh][dd] = dot2(e2,  bch(au[j][dd]),  accN[q][hh][dd]);
                    accN[q][hh][dd] = dot2(eg2, bch(bu[j][dd]),  accN[q][hh][dd]);
                    accD[q][hh][dd] = dot2(e2,  bch(mu_[j][dd]), accD[q][hh][dd]);
                }
            }
        }
    }
    __syncthreads();

    // ---- cross-ks partials (alias over dead A2s/B2s) ----
    float* REDN = (float*)A2s;    // 4096 f
    float* REDD = (float*)B2s;    // 4096 f
    #pragma unroll
    for (int q = 0; q < 2; ++q)
    #pragma unroll
    for (int hh = 0; hh < 2; ++hh) {
        const int c = (q * 8 + hb + hh) * 32 + dg * 4;
        *(float4*)&REDN[ks * 512 + c] =
            make_float4(accN[q][hh][0], accN[q][hh][1], accN[q][hh][2], accN[q][hh][3]);
        *(float4*)&REDD[ks * 512 + c] =
            make_float4(accD[q][hh][0], accD[q][hh][1], accD[q][hh][2], accD[q][hh][3]);
    }
    __syncthreads();

    // ---- reduce over ks + divide (128 threads own one float4 slot each) ----
    if (t < 128) {
        float4 n = make_float4(0.f,0.f,0.f,0.f), d = make_float4(0.f,0.f,0.f,0.f);
        #pragma unroll
        for (int s = 0; s < 8; ++s) {
            const float4 nn = *(const float4*)&REDN[s * 512 + t * 4];
            const float4 dd = *(const float4*)&REDD[s * 512 + t * 4];
            n.x += nn.x; n.y += nn.y; n.z += nn.z; n.w += nn.w;
            d.x += dd.x; d.y += dd.y; d.z += dd.z; d.w += dd.w;
        }
        float4 x;
        x.x = n.x / fmaxf(d.x, 1e-30f);
        x.y = n.y / fmaxf(d.y, 1e-30f);
        x.z = n.z / fmaxf(d.z, 1e-30f);
        x.w = n.w / fmaxf(d.w, 1e-30f);
        *(float4*)&XSH[t * 4] = x;
    }
    __syncthreads();

    // ---- epilogue: out[b,q0+q,:] = x @ wo + bo. thread = (q, j), t<128 ----
    if (t < 128) {
        const int q = t >> 6, j = t & 63;
        float acc = bo[j];
        const float4* xq = (const float4*)&XSH[q * 256];
        #pragma unroll 8
        for (int c4 = 0; c4 < 64; ++c4) {
            const float4 xv = xq[c4];
            const int c = c4 * 4;
            acc = fmaf(xv.x, wo[(c + 0) * NH + j], acc);
            acc = fmaf(xv.y, wo[(c + 1) * NH + j], acc);
            acc = fmaf(xv.z, wo[(c + 2) * NH + j], acc);
            acc = fmaf(xv.w, wo[(c + 3) * NH + j], acc);
        }
        out[((size_t)b * LQ + q0 + q) * NH + j] = acc;
    }
}

extern "C" void kernel_launch(void* const* d_in, const int* in_sizes, int n_in,
                              void* d_out, int out_size, void* d_ws, size_t ws_size,
                              hipStream_t stream) {
    const float* qtt      = (const float*)d_in[0];
    const float* ktt      = (const float*)d_in[1];
    const float* value    = (const float*)d_in[2];
    const int*   emb_mask = (const int*)  d_in[3];
    const float* w_time   = (const float*)d_in[4];
    const float* b_time   = (const float*)d_in[5];
    const float* w_per    = (const float*)d_in[6];
    const float* b_per    = (const float*)d_in[7];
    const float* w_decay  = (const float*)d_in[8];
    const float* vt_w1    = (const float*)d_in[9];
    const float* vt_b1    = (const float*)d_in[10];
    const float* ln_g     = (const float*)d_in[11];
    const float* ln_b     = (const float*)d_in[12];
    const float* vt_w2    = (const float*)d_in[13];
    const float* vt_b2    = (const float*)d_in[14];
    const float* wq       = (const float*)d_in[15];
    const float* bq       = (const float*)d_in[16];
    const float* wk       = (const float*)d_in[17];
    const float* bk       = (const float*)d_in[18];
    const float* wo       = (const float*)d_in[19];
    const float* bo       = (const float*)d_in[20];
    float* out = (float*)d_out;

    unsigned* wsu = (unsigned*)d_ws;
    unsigned* A2g = wsu;               // 32768 u (1024 k2 x 32 d)
    unsigned* B2g = wsu + 32768;
    unsigned* M2g = wsu + 65536;
    float*    qew = (float*)(wsu + 98304);   // 32768 f
    float*    kew = (float*)(wsu + 131072);  // 65536 f

    hipLaunchKernelGGL(prep_kernel, dim3(896), dim3(256), 0, stream,
                       qtt, ktt, value, emb_mask, w_time, b_time, w_per, b_per,
                       vt_w1, vt_b1, ln_g, ln_b, vt_w2, vt_b2,
                       wq, bq, wk, bk, A2g, B2g, M2g, qew, kew);

    hipLaunchKernelGGL(attn_kernel, dim3(512), dim3(256), 0, stream,
                       qtt, ktt, w_decay, A2g, B2g, M2g, qew, kew, wo, bo, out);
}